// Round 6
// baseline (682.699 us; speedup 1.0000x reference)
//
#include <hip/hip_runtime.h>
#include <hip/hip_bf16.h>
#include <math.h>

#define BB 64
#define SS 2048
#define MT (SS*BB)   // 131072 rows of the big GEMM
#define NT 16        // K-tiles (K=1024, BK=64)

typedef __attribute__((ext_vector_type(4))) float f4;
typedef __attribute__((ext_vector_type(8))) short s8;

__device__ __forceinline__ unsigned short f2bf(float x) {
  union { float f; unsigned u; } v; v.f = x;
  unsigned r = v.u + 0x7FFFu + ((v.u >> 16) & 1u);   // RNE
  return (unsigned short)(r >> 16);
}
__device__ __forceinline__ float bf2f(unsigned short x) {
  union { unsigned u; float f; } v; v.u = ((unsigned)x) << 16;
  return v.f;
}
__device__ __forceinline__ float fast_tanh(float x) {
  float t = __expf(2.0f * x);
  return 1.0f - 2.0f * __builtin_amdgcn_rcpf(t + 1.0f);
}

#define GLD16(gp, lp) __builtin_amdgcn_global_load_lds( \
    (const __attribute__((address_space(1))) void*)(gp), \
    (__attribute__((address_space(3))) void*)(lp), 16, 0, 0)
#define WAITV4() asm volatile("s_waitcnt vmcnt(4)" ::: "memory")
#define BAR()    __builtin_amdgcn_s_barrier()

// ---- coalesced pack: f32 (rows x stride) -> swizzled bf16 units.
// Layout: [panel(256 rows)][kt 0..15][h=row>>7][r=row&127][8 slots x 8 shorts]
// where slot position s' at row r holds source cols kt*64 + (s'^(r&7))*8 ..+8.
// grid: (rows/64, 4); block 256.
__global__ void k_pack(const float* __restrict__ src, unsigned short* __restrict__ dst,
                       int stride) {
  __shared__ float ls[64][260];
  int g = blockIdx.x, cb = blockIdx.y, tid = threadIdx.x;
  int cl = (tid & 63) * 4, rbk = tid >> 6;
  const float* s0 = src + (size_t)(g * 64) * stride + cb * 256 + cl;
  #pragma unroll
  for (int it = 0; it < 16; ++it) {
    int rr = it * 4 + rbk;
    *(f4*)&ls[rr][cl] = *(const f4*)(s0 + (size_t)rr * stride);
  }
  __syncthreads();
  int kt_l = tid >> 6;              // 0..3
  int rr = tid & 63;
  int kt = cb * 4 + kt_l;
  int grow = g * 64 + rr;
  int panel = grow >> 8, pr = grow & 255, h = pr >> 7, r = pr & 127;
  unsigned short* d = dst + (((size_t)panel * 16 + kt) * 2 + h) * 8192 + r * 64;
  int rx = r & 7;
  #pragma unroll
  for (int sp = 0; sp < 8; ++sp) {
    const float* q = &ls[rr][kt_l * 64 + ((sp ^ rx) * 8)];
    f4 x0 = *(const f4*)q, x1 = *(const f4*)(q + 4);
    s8 o;
    #pragma unroll
    for (int j = 0; j < 4; ++j) { o[j] = (short)f2bf(x0[j]); o[4 + j] = (short)f2bf(x1[j]); }
    *(s8*)(d + sp * 8) = o;
  }
}

// ---- hp[b][a] = hidden[b,:]·Wd[a,:] + bias[a]
__global__ void k_hp(const float* __restrict__ hidden, const float* __restrict__ w,
                     const float* __restrict__ wbias, float* __restrict__ hp) {
  __shared__ float hs[1024];
  int b = blockIdx.x, tid = threadIdx.x;
  for (int i = tid; i < 1024; i += 256) hs[i] = hidden[b * 1024 + i];
  __syncthreads();
  int a = blockIdx.y * 256 + tid;
  const f4* wd = (const f4*)(w + a * 2048 + 1024);
  const f4* hv = (const f4*)hs;
  float acc = wbias[a];
  #pragma unroll 8
  for (int d = 0; d < 256; ++d) {
    f4 x = wd[d], y = hv[d];
    acc += x[0]*y[0] + x[1]*y[1] + x[2]*y[2] + x[3]*y[3];
  }
  hp[b * 1024 + a] = acc;
}

// ---- fused GEMM: 256x256 tile, BK=64, 8 waves (2M x 4N), per-wave 128x64.
// A double-buffered in LDS (2 x 32KB). B (L2-resident) loaded straight to
// registers, 2 phases ahead. 4 phases / K-tile, ONE barrier per phase,
// next-phase ds_reads issued under current MFMA. partials[p][b][s], p=bn*4+wc.
__global__ __launch_bounds__(512, 2) void k_gemm(
    const unsigned short* __restrict__ Avbs, const unsigned short* __restrict__ Wbs,
    const float* __restrict__ hp, const float* __restrict__ vw,
    float* __restrict__ part, int bm0, int nbm) {
  extern __shared__ char smem[];
  int bid = blockIdx.x;
  int nwg = nbm * 4;
  int wg = bid;
  if ((nwg & 7) == 0) { int cpx = nwg >> 3; wg = (bid & 7) * cpx + (bid >> 3); }
  int bn = wg & 3;              // bn fastest: 4 readers of one A-tile on one XCD
  int bmL = wg >> 2;
  int tid = threadIdx.x, lane = tid & 63;
  int wid = tid >> 6, wr = wid >> 2, wc = wid & 3;
  int c = lane & 15, kq = lane >> 4;

  // swizzled slot offsets (bytes for LDS, elements for global B)
  int sx0 = ((kq) ^ (c & 7)) << 4;
  int sx1 = ((4 + kq) ^ (c & 7)) << 4;
  int sxe0 = sx0 >> 1, sxe1 = sx1 >> 1;

  // B per-ni lane-constant pointers (panel bn, kt=0)
  const unsigned short* Bt = Wbs + (size_t)bn * 262144;
  int nrb = wc * 64 + c;
  const unsigned short* Bp0 = Bt + ((nrb >> 7) * 8192 + (nrb & 127) * 64);
  int nr1 = nrb + 16;
  const unsigned short* Bp1 = Bt + ((nr1 >> 7) * 8192 + (nr1 & 127) * 64);
  int nr2 = nrb + 32;
  const unsigned short* Bp2 = Bt + ((nr2 >> 7) * 8192 + (nr2 & 127) * 64);
  int nr3 = nrb + 48;
  const unsigned short* Bp3 = Bt + ((nr3 >> 7) * 8192 + (nr3 & 127) * 64);

  const unsigned short* Abase = Avbs + (size_t)bmL * 262144 + tid * 8;
  auto stageA = [&](int tt, int h) {
    char* d = smem + (tt & 1) * 32768 + h * 16384 + tid * 16;
    const unsigned short* s = Abase + ((size_t)tt * 2 + h) * 8192;
    GLD16(s, d);
    GLD16(s + 4096, d + 8192);
  };

  f4 acc[8][4];
  f4 z = {0.f, 0.f, 0.f, 0.f};
  #pragma unroll
  for (int i = 0; i < 8; ++i)
    #pragma unroll
    for (int j = 0; j < 4; ++j) acc[i][j] = z;

  s8 vaA[4], vaB[4], vb0[4], vb1[4];

#define LDSA(DST, BASE, SX) { const char* p_ = (BASE) + (SX); \
    DST[0] = *(const s8*)(p_);        DST[1] = *(const s8*)(p_ + 2048); \
    DST[2] = *(const s8*)(p_ + 4096); DST[3] = *(const s8*)(p_ + 6144); }
#define LDB4(DST, TOFF, SXE) { \
    DST[0] = *(const s8*)(Bp0 + (TOFF) + (SXE)); \
    DST[1] = *(const s8*)(Bp1 + (TOFF) + (SXE)); \
    DST[2] = *(const s8*)(Bp2 + (TOFF) + (SXE)); \
    DST[3] = *(const s8*)(Bp3 + (TOFF) + (SXE)); }
#define MM(mh, VA, VB) { \
    __builtin_amdgcn_s_setprio(1); \
    _Pragma("unroll") \
    for (int m_ = 0; m_ < 4; ++m_) { \
      acc[(mh)*4+m_][0] = __builtin_amdgcn_mfma_f32_16x16x32_bf16(VA[m_], VB[0], acc[(mh)*4+m_][0], 0, 0, 0); \
      acc[(mh)*4+m_][1] = __builtin_amdgcn_mfma_f32_16x16x32_bf16(VA[m_], VB[1], acc[(mh)*4+m_][1], 0, 0, 0); \
      acc[(mh)*4+m_][2] = __builtin_amdgcn_mfma_f32_16x16x32_bf16(VA[m_], VB[2], acc[(mh)*4+m_][2], 0, 0, 0); \
      acc[(mh)*4+m_][3] = __builtin_amdgcn_mfma_f32_16x16x32_bf16(VA[m_], VB[3], acc[(mh)*4+m_][3], 0, 0, 0); \
    } \
    __builtin_amdgcn_s_setprio(0); }

  // prologue: stage A(0) fully, load B(0,ks0) to regs
  stageA(0, 0); stageA(0, 1);
  LDB4(vb0, 0, sxe0);
  WAITV4();            // own A(0) stages landed (vb0 may fly; counted wait at use)
  BAR();

  #pragma unroll 1
  for (int t = 0; t < NT; ++t) {
    const char* bufb = smem + (t & 1) * 32768 + wr * 16384 + c * 128;
    // P0: read A(mh0,ks0)+A(mh1,ks0); stage A-h0(t+1); load B(t,ks1); MFMA(mh0,ks0)
    LDSA(vaA, bufb, sx0);
    LDSA(vaB, bufb + 8192, sx0);
    if (t < 15) stageA(t + 1, 0);
    LDB4(vb1, t * 16384, sxe1);
    MM(0, vaA, vb0);
    BAR();
    // P1: read A(mh0,ks1); stage A-h1(t+1); MFMA(mh1,ks0)
    LDSA(vaA, bufb, sx1);
    if (t < 15) stageA(t + 1, 1);
    MM(1, vaB, vb0);
    BAR();
    // P2: read A(mh1,ks1); load B(t+1,ks0); MFMA(mh0,ks1)
    LDSA(vaB, bufb + 8192, sx1);
    if (t < 15) LDB4(vb0, (t + 1) * 16384, sxe0);
    MM(0, vaA, vb1);
    BAR();
    // P3: own-stage counted drain; MFMA(mh1,ks1)
    WAITV4();
    MM(1, vaB, vb1);
    BAR();
  }
#undef LDSA
#undef LDB4
#undef MM

  // ---- epilogue: stage hp[b][bn*256..+255] (64x256 f32 = 64KB) into LDS
  {
    const float* hprow = hp + bn * 256;
    float* lhp = (float*)smem;
    #pragma unroll
    for (int qd = 0; qd < 8; ++qd) {
      int i = qd * 512 + tid;
      int b = i >> 6, col4 = i & 63;
      *(f4*)(lhp + b * 256 + col4 * 4) = *(const f4*)(hprow + (size_t)b * 1024 + col4 * 4);
    }
  }
  __syncthreads();
  const float* lhpf = (const float*)smem;

  int lg = kq;
  int bm = bm0 + bmL;
  float rs[8][4];
  #pragma unroll
  for (int mi = 0; mi < 8; ++mi)
    #pragma unroll
    for (int j = 0; j < 4; ++j) rs[mi][j] = 0.f;
  #pragma unroll
  for (int ni = 0; ni < 4; ++ni) {
    int colL = wc * 64 + ni * 16 + c;
    float vwa = vw[bn * 256 + colL];
    #pragma unroll
    for (int mi = 0; mi < 8; ++mi) {
      #pragma unroll
      for (int j = 0; j < 4; ++j) {
        int r = wr * 128 + mi * 16 + lg * 4 + j;
        int b = r & 63;
        float x = acc[mi][ni][j] + lhpf[b * 256 + colL];
        rs[mi][j] += fast_tanh(x) * vwa;
      }
    }
  }
  #pragma unroll
  for (int off = 1; off < 16; off <<= 1) {
    #pragma unroll
    for (int mi = 0; mi < 8; ++mi)
      #pragma unroll
      for (int j = 0; j < 4; ++j)
        rs[mi][j] += __shfl_xor(rs[mi][j], off, 64);
  }
  if (c == 0) {
    int p = bn * 4 + wc;
    #pragma unroll
    for (int mi = 0; mi < 8; ++mi)
      #pragma unroll
      for (int j = 0; j < 4; ++j) {
        int m = bm * 256 + wr * 128 + mi * 16 + lg * 4 + j;
        int b = m & 63, s = m >> 6;
        part[(size_t)p * MT + b * SS + s] = rs[mi][j];
      }
  }
}

// ---- sum 16 partials -> scores, softmax over s per b -> weights[b][s]
__global__ void k_softmax(const float* __restrict__ part, float* __restrict__ wt) {
  int b = blockIdx.x, tid = threadIdx.x, lane = tid & 63, wid = tid >> 6;
  __shared__ float red[8];
  float sc[8];
  float mx = -1e30f;
  #pragma unroll
  for (int i = 0; i < 8; ++i) {
    int s = tid + i * 256;
    float a = 0.f;
    #pragma unroll
    for (int p = 0; p < 16; ++p) a += part[(size_t)p * MT + b * SS + s];
    sc[i] = a; mx = fmaxf(mx, a);
  }
  for (int o = 1; o < 64; o <<= 1) mx = fmaxf(mx, __shfl_xor(mx, o, 64));
  if (lane == 0) red[wid] = mx;
  __syncthreads();
  mx = fmaxf(fmaxf(red[0], red[1]), fmaxf(red[2], red[3]));
  float sum = 0.f;
  #pragma unroll
  for (int i = 0; i < 8; ++i) { sc[i] = expf(sc[i] - mx); sum += sc[i]; }
  for (int o = 1; o < 64; o <<= 1) sum += __shfl_xor(sum, o, 64);
  if (lane == 0) red[4 + wid] = sum;
  __syncthreads();
  sum = red[4] + red[5] + red[6] + red[7];
  float inv = 1.f / sum;
  #pragma unroll
  for (int i = 0; i < 8; ++i) wt[b * SS + tid + i * 256] = sc[i] * inv;
}

// ---- context from swizzled bf16 units
__global__ void k_ctx_bfs(const unsigned short* __restrict__ vbs, const float* __restrict__ wt,
                          float* __restrict__ ctxp) {
  int b = blockIdx.x, cch = blockIdx.y, tid = threadIdx.x;
  int e = tid * 4;
  int kt = e >> 6, sl = (e >> 3) & 7, off = e & 7;
  f4 acc = {0.f, 0.f, 0.f, 0.f};
  int s0 = cch * 128;
  const float* wrow = wt + b * SS;
  #pragma unroll 4
  for (int s = s0; s < s0 + 128; ++s) {
    float ws = wrow[s];
    int row = s * 64 + b;
    int panel = row >> 8, pr = row & 255, h = pr >> 7, r = pr & 127;
    size_t addr = (((size_t)panel * 16 + kt) * 2 + h) * 8192 + r * 64 + ((sl ^ (r & 7)) << 3) + off;
    ushort4 u = *(const ushort4*)(vbs + addr);
    acc[0] += bf2f(u.x) * ws;
    acc[1] += bf2f(u.y) * ws;
    acc[2] += bf2f(u.z) * ws;
    acc[3] += bf2f(u.w) * ws;
  }
  *(f4*)(ctxp + (size_t)(cch * 64 + b) * 1024 + tid * 4) = acc;
}

// ---- context fallback from f32 v (multi-chunk only)
__global__ void k_ctx_f32(const float* __restrict__ v, const float* __restrict__ wt,
                          float* __restrict__ ctxp) {
  int b = blockIdx.x, cch = blockIdx.y, tid = threadIdx.x;
  f4 acc = {0.f, 0.f, 0.f, 0.f};
  int s0 = cch * 128;
  const float* wrow = wt + b * SS;
  #pragma unroll 4
  for (int s = s0; s < s0 + 128; ++s) {
    float ws = wrow[s];
    const f4* vp = (const f4*)(v + (size_t)(s * 64 + b) * 1024);
    acc += vp[tid] * ws;
  }
  *(f4*)(ctxp + (size_t)(cch * 64 + b) * 1024 + tid * 4) = acc;
}

__global__ void k_out(const float* __restrict__ ctxp, float* __restrict__ out) {
  int b = blockIdx.x, tid = threadIdx.x;
  f4 acc = {0.f, 0.f, 0.f, 0.f};
  #pragma unroll
  for (int cch = 0; cch < 16; ++cch)
    acc += *(const f4*)(ctxp + (size_t)(cch * 64 + b) * 1024 + tid * 4);
  *(f4*)(out + b * 1024 + tid * 4) = acc;
}

extern "C" void kernel_launch(void* const* d_in, const int* in_sizes, int n_in,
                              void* d_out, int out_size, void* d_ws, size_t ws_size,
                              hipStream_t stream) {
  const float* hidden = (const float*)d_in[0];
  const float* v      = (const float*)d_in[1];   // (S, B, ENC) rows s*64+b
  const float* ww     = (const float*)d_in[2];   // (1024, 2048)
  const float* wbias  = (const float*)d_in[3];   // (1024)
  const float* vwgt   = (const float*)d_in[4];   // (1, 1024)
  float* out = (float*)d_out;

  char* ws = (char*)d_ws;
  float*          hp   = (float*)(ws);                                   // 256 KB
  unsigned short* wbs  = (unsigned short*)(ws + 262144);                 // 2 MB
  float*          part = (float*)(ws + 262144 + 2097152);                // 8 MB
  float*          wt   = (float*)(ws + 262144 + 2097152 + 8388608);      // 512 KB
  float*          ctxp = (float*)(ws + 262144 + 2097152 + 8388608 + 524288); // 4 MB
  size_t fixed = 262144 + 2097152 + 8388608 + 524288 + 4194304;
  unsigned short* vbs  = (unsigned short*)(ws + fixed);

  size_t avail = (ws_size > fixed) ? (ws_size - fixed) : 0;
  long rows_chunk = (long)(avail / 2048) & ~511L;      // multiple of 512 rows
  if (rows_chunk > MT) rows_chunk = MT;
  if (rows_chunk < 512) rows_chunk = 512;
  int nchunks = (int)((MT + rows_chunk - 1) / rows_chunk);

  hipFuncSetAttribute((const void*)k_gemm, hipFuncAttributeMaxDynamicSharedMemorySize, 65536);

  k_pack<<<dim3(16, 4), 256, 0, stream>>>(ww, wbs, 2048);
  k_hp<<<dim3(64, 4), 256, 0, stream>>>(hidden, ww, wbias, hp);

  for (long r0 = 0; r0 < MT; r0 += rows_chunk) {
    long nr = MT - r0; if (nr > rows_chunk) nr = rows_chunk;
    int nbm = (int)(nr / 256);
    k_pack<<<dim3((int)(nr / 64), 4), 256, 0, stream>>>(v + (size_t)r0 * 1024, vbs, 1024);
    k_gemm<<<nbm * 4, 512, 65536, stream>>>(vbs, wbs, hp, vwgt, part, (int)(r0 / 256), nbm);
  }

  k_softmax<<<64, 256, 0, stream>>>(part, wt);
  if (nchunks == 1)
    k_ctx_bfs<<<dim3(64, 16), 256, 0, stream>>>(vbs, wt, ctxp);
  else
    k_ctx_f32<<<dim3(64, 16), 256, 0, stream>>>(v, wt, ctxp);
  k_out<<<64, 256, 0, stream>>>(ctxp, out);
}

// Round 7
// 576.375 us; speedup vs baseline: 1.1845x; 1.1845x over previous
//
#include <hip/hip_runtime.h>
#include <hip/hip_bf16.h>
#include <math.h>

#define BB 64
#define SS 2048
#define MT (SS*BB)   // 131072 rows of the big GEMM
#define NT 16        // K-tiles (K=1024, BK=64)

typedef __attribute__((ext_vector_type(4))) float f4;
typedef __attribute__((ext_vector_type(8))) short s8;

__device__ __forceinline__ unsigned short f2bf(float x) {
  union { float f; unsigned u; } v; v.f = x;
  unsigned r = v.u + 0x7FFFu + ((v.u >> 16) & 1u);   // RNE
  return (unsigned short)(r >> 16);
}
__device__ __forceinline__ float bf2f(unsigned short x) {
  union { unsigned u; float f; } v; v.u = ((unsigned)x) << 16;
  return v.f;
}
__device__ __forceinline__ float fast_tanh(float x) {
  float t = __expf(2.0f * x);
  return 1.0f - 2.0f * __builtin_amdgcn_rcpf(t + 1.0f);
}

#define GLD16(gp, lp) __builtin_amdgcn_global_load_lds( \
    (const __attribute__((address_space(1))) void*)(gp), \
    (__attribute__((address_space(3))) void*)(lp), 16, 0, 0)
#define WAITV4() asm volatile("s_waitcnt vmcnt(4)" ::: "memory")
#define WAITV0() asm volatile("s_waitcnt vmcnt(0)" ::: "memory")
#define BAR()    __builtin_amdgcn_s_barrier()
#define SCHED0() __builtin_amdgcn_sched_barrier(0)

// ---- coalesced pack: f32 (rows x stride) -> swizzled bf16 units.
// Layout: [panel(256 rows)][kt 0..15][h=row>>7][r=row&127][8 slots x 8 shorts]
// where slot position s' at row r holds source cols kt*64 + (s'^(r&7))*8 ..+8.
// grid: (rows/64, 4); block 256.
__global__ void k_pack(const float* __restrict__ src, unsigned short* __restrict__ dst,
                       int stride) {
  __shared__ float ls[64][260];
  int g = blockIdx.x, cb = blockIdx.y, tid = threadIdx.x;
  int cl = (tid & 63) * 4, rbk = tid >> 6;
  const float* s0 = src + (size_t)(g * 64) * stride + cb * 256 + cl;
  #pragma unroll
  for (int it = 0; it < 16; ++it) {
    int rr = it * 4 + rbk;
    *(f4*)&ls[rr][cl] = *(const f4*)(s0 + (size_t)rr * stride);
  }
  __syncthreads();
  int kt_l = tid >> 6;              // 0..3
  int rr = tid & 63;
  int kt = cb * 4 + kt_l;
  int grow = g * 64 + rr;
  int panel = grow >> 8, pr = grow & 255, h = pr >> 7, r = pr & 127;
  unsigned short* d = dst + (((size_t)panel * 16 + kt) * 2 + h) * 8192 + r * 64;
  int rx = r & 7;
  #pragma unroll
  for (int sp = 0; sp < 8; ++sp) {
    const float* q = &ls[rr][kt_l * 64 + ((sp ^ rx) * 8)];
    f4 x0 = *(const f4*)q, x1 = *(const f4*)(q + 4);
    s8 o;
    #pragma unroll
    for (int j = 0; j < 4; ++j) { o[j] = (short)f2bf(x0[j]); o[4 + j] = (short)f2bf(x1[j]); }
    *(s8*)(d + sp * 8) = o;
  }
}

// ---- hp[b][a] = hidden[b,:]·Wd[a,:] + bias[a]
__global__ void k_hp(const float* __restrict__ hidden, const float* __restrict__ w,
                     const float* __restrict__ wbias, float* __restrict__ hp) {
  __shared__ float hs[1024];
  int b = blockIdx.x, tid = threadIdx.x;
  for (int i = tid; i < 1024; i += 256) hs[i] = hidden[b * 1024 + i];
  __syncthreads();
  int a = blockIdx.y * 256 + tid;
  const f4* wd = (const f4*)(w + a * 2048 + 1024);
  const f4* hv = (const f4*)hs;
  float acc = wbias[a];
  #pragma unroll 8
  for (int d = 0; d < 256; ++d) {
    f4 x = wd[d], y = hv[d];
    acc += x[0]*y[0] + x[1]*y[1] + x[2]*y[2] + x[3]*y[3];
  }
  hp[b * 1024 + a] = acc;
}

// ---- fused GEMM: 256x256 tile, BK=64, 8 waves (2M x 4N), per-wave 128x64.
// A,B double-buffered in LDS (2 x 64KB, 4 units of 16KB). Fragment reads
// software-pipelined one phase ahead (vaC/vaN ping-pong); 2 barriers per
// K-tile (end-P1 + boundary). Counted vmcnt(4) at boundary, never 0 mid-loop.
// partials[p][b][s], p = bn*4 + wc.
__global__ __launch_bounds__(512, 1) void k_gemm(
    const unsigned short* __restrict__ Avbs, const unsigned short* __restrict__ Wbs,
    const float* __restrict__ hp, const float* __restrict__ vw,
    float* __restrict__ part, int bm0, int nbm) {
  extern __shared__ char smem[];
  int bid = blockIdx.x;
  int nwg = nbm * 4;
  int wg = bid;
  if ((nwg & 7) == 0) { int cpx = nwg >> 3; wg = (bid & 7) * cpx + (bid >> 3); }
  int bn = wg & 3;              // bn fastest: 4 readers of one A-tile on one XCD
  int bmL = wg >> 2;
  int tid = threadIdx.x, lane = tid & 63;
  int wid = tid >> 6, wr = wid >> 2, wc = wid & 3;
  int c = lane & 15, kq = lane >> 4;

  // swizzled slot byte offsets within a 128B row (8 slots x 16B)
  int sx0 = ((kq) ^ (c & 7)) << 4;
  int sx1 = ((4 + kq) ^ (c & 7)) << 4;
  int aoff = wr * 16384 + c * 128;                                   // + mh*8192 + mi*2048 + sx
  int boff = 32768 + (wc >> 1) * 16384 + ((wc & 1) * 64 + c) * 128;  // + ni*2048 + sx

  const unsigned short* Abase = Avbs + (size_t)bmL * 262144 + tid * 8;
  const unsigned short* Bbase = Wbs + (size_t)bn * 262144 + tid * 8;
  auto stage = [&](int tt, int u) {   // u: 0=A-h0, 1=A-h1, 2=B-h0, 3=B-h1
    char* d = smem + (tt & 1) * 65536 + u * 16384 + tid * 16;
    const unsigned short* s = ((u & 2) ? Bbase : Abase) + ((size_t)tt * 2 + (u & 1)) * 8192;
    GLD16(s, d);
    GLD16(s + 4096, d + 8192);
  };

  f4 acc[8][4];
  f4 z = {0.f, 0.f, 0.f, 0.f};
  #pragma unroll
  for (int i = 0; i < 8; ++i)
    #pragma unroll
    for (int j = 0; j < 4; ++j) acc[i][j] = z;

  s8 vaC[4], vaN[4], vb0[4], vb1[4];

#define LDSA(DST, BASE, SX) { const char* p_ = (BASE) + (SX); \
    DST[0] = *(const s8*)(p_);        DST[1] = *(const s8*)(p_ + 2048); \
    DST[2] = *(const s8*)(p_ + 4096); DST[3] = *(const s8*)(p_ + 6144); }
#define LDB(RB, DST, SX) { const char* bb_ = (RB) + boff + (SX); \
    DST[0] = *(const s8*)(bb_);        DST[1] = *(const s8*)(bb_ + 2048); \
    DST[2] = *(const s8*)(bb_ + 4096); DST[3] = *(const s8*)(bb_ + 6144); }
#define MM(mh, VA, VB) { \
    __builtin_amdgcn_s_setprio(1); \
    _Pragma("unroll") \
    for (int m_ = 0; m_ < 4; ++m_) { \
      acc[(mh)*4+m_][0] = __builtin_amdgcn_mfma_f32_16x16x32_bf16(VA[m_], VB[0], acc[(mh)*4+m_][0], 0, 0, 0); \
      acc[(mh)*4+m_][1] = __builtin_amdgcn_mfma_f32_16x16x32_bf16(VA[m_], VB[1], acc[(mh)*4+m_][1], 0, 0, 0); \
      acc[(mh)*4+m_][2] = __builtin_amdgcn_mfma_f32_16x16x32_bf16(VA[m_], VB[2], acc[(mh)*4+m_][2], 0, 0, 0); \
      acc[(mh)*4+m_][3] = __builtin_amdgcn_mfma_f32_16x16x32_bf16(VA[m_], VB[3], acc[(mh)*4+m_][3], 0, 0, 0); \
    } \
    __builtin_amdgcn_s_setprio(0); }

  // prologue: A(0),B(0),B(1) staged; read first fragments
  stage(0, 0); stage(0, 1); stage(0, 2); stage(0, 3);
  stage(1, 2); stage(1, 3);
  WAITV4();            // A(0)+B(0) landed; B(1) flies
  BAR();
  SCHED0();
  {
    const char* rb = smem;
    LDSA(vaC, rb + aoff, sx0);      // A(0, mh0, ks0)
    LDB(rb, vb0, sx0);              // B(0, ks0)
  }

  #pragma unroll 1
  for (int t = 0; t < NT; ++t) {
    const char* rb = smem + (t & 1) * 65536;
    const char* ab = rb + aoff;
    // P0: MFMA(mh0,ks0); pipeline reads A(mh0,ks1), B(ks1); stage A(t+1,h0)
    if (t < 15) stage(t + 1, 0);
    MM(0, vaC, vb0);
    LDSA(vaN, ab, sx1);
    LDB(rb, vb1, sx1);
    // P1: MFMA(mh0,ks1); pipeline read A(mh1,ks0); stage A(t+1,h1)
    if (t < 15) stage(t + 1, 1);
    MM(0, vaN, vb1);
    LDSA(vaC, ab + 8192, sx0);
    SCHED0();
    BAR();               // end-P1: all waves' B(t) LDS reads have drained
    SCHED0();
    // P2: MFMA(mh1,ks0); pipeline read A(mh1,ks1); stage B(t+2,h0) into current buf
    if (t < 14) stage(t + 2, 2);
    MM(1, vaC, vb0);
    LDSA(vaN, ab + 8192, sx1);
    // P3: MFMA(mh1,ks1); stage B(t+2,h1)
    if (t < 14) stage(t + 2, 3);
    MM(1, vaN, vb1);
    // boundary: A(t+1)+B(t+1) guaranteed landed; B(t+2) may fly
    if (t < 15) {
      if (t < 14) WAITV4(); else WAITV0();
      SCHED0();
      BAR();
      SCHED0();
      const char* nrb = smem + ((t + 1) & 1) * 65536;
      LDSA(vaC, nrb + aoff, sx0);   // A(t+1, mh0, ks0)
      LDB(nrb, vb0, sx0);           // B(t+1, ks0)
    }
  }
#undef LDSA
#undef LDB
#undef MM

  // ---- epilogue: stage hp[b][bn*256..+255] (64x256 f32 = 64KB) into LDS
  __syncthreads();
  {
    const float* hprow = hp + bn * 256;
    float* lhp = (float*)smem;
    #pragma unroll
    for (int qd = 0; qd < 8; ++qd) {
      int i = qd * 512 + tid;
      int b = i >> 6, col4 = i & 63;
      *(f4*)(lhp + b * 256 + col4 * 4) = *(const f4*)(hprow + (size_t)b * 1024 + col4 * 4);
    }
  }
  __syncthreads();
  const float* lhpf = (const float*)smem;

  int lg = kq;
  int bm = bm0 + bmL;
  float rs[8][4];
  #pragma unroll
  for (int mi = 0; mi < 8; ++mi)
    #pragma unroll
    for (int j = 0; j < 4; ++j) rs[mi][j] = 0.f;
  #pragma unroll
  for (int ni = 0; ni < 4; ++ni) {
    int colL = wc * 64 + ni * 16 + c;
    float vwa = vw[bn * 256 + colL];
    #pragma unroll
    for (int mi = 0; mi < 8; ++mi) {
      #pragma unroll
      for (int j = 0; j < 4; ++j) {
        int r = wr * 128 + mi * 16 + lg * 4 + j;
        int b = r & 63;
        float x = acc[mi][ni][j] + lhpf[b * 256 + colL];
        rs[mi][j] += fast_tanh(x) * vwa;
      }
    }
  }
  #pragma unroll
  for (int off = 1; off < 16; off <<= 1) {
    #pragma unroll
    for (int mi = 0; mi < 8; ++mi)
      #pragma unroll
      for (int j = 0; j < 4; ++j)
        rs[mi][j] += __shfl_xor(rs[mi][j], off, 64);
  }
  if (c == 0) {
    int p = bn * 4 + wc;
    #pragma unroll
    for (int mi = 0; mi < 8; ++mi)
      #pragma unroll
      for (int j = 0; j < 4; ++j) {
        int m = bm * 256 + wr * 128 + mi * 16 + lg * 4 + j;
        int b = m & 63, s = m >> 6;
        part[(size_t)p * MT + b * SS + s] = rs[mi][j];
      }
  }
}

// ---- sum 16 partials -> scores, softmax over s per b -> weights[b][s]
__global__ void k_softmax(const float* __restrict__ part, float* __restrict__ wt) {
  int b = blockIdx.x, tid = threadIdx.x, lane = tid & 63, wid = tid >> 6;
  __shared__ float red[8];
  float sc[8];
  float mx = -1e30f;
  #pragma unroll
  for (int i = 0; i < 8; ++i) {
    int s = tid + i * 256;
    float a = 0.f;
    #pragma unroll
    for (int p = 0; p < 16; ++p) a += part[(size_t)p * MT + b * SS + s];
    sc[i] = a; mx = fmaxf(mx, a);
  }
  for (int o = 1; o < 64; o <<= 1) mx = fmaxf(mx, __shfl_xor(mx, o, 64));
  if (lane == 0) red[wid] = mx;
  __syncthreads();
  mx = fmaxf(fmaxf(red[0], red[1]), fmaxf(red[2], red[3]));
  float sum = 0.f;
  #pragma unroll
  for (int i = 0; i < 8; ++i) { sc[i] = expf(sc[i] - mx); sum += sc[i]; }
  for (int o = 1; o < 64; o <<= 1) sum += __shfl_xor(sum, o, 64);
  if (lane == 0) red[4 + wid] = sum;
  __syncthreads();
  sum = red[4] + red[5] + red[6] + red[7];
  float inv = 1.f / sum;
  #pragma unroll
  for (int i = 0; i < 8; ++i) wt[b * SS + tid + i * 256] = sc[i] * inv;
}

// ---- context from swizzled bf16 units
__global__ void k_ctx_bfs(const unsigned short* __restrict__ vbs, const float* __restrict__ wt,
                          float* __restrict__ ctxp) {
  int b = blockIdx.x, cch = blockIdx.y, tid = threadIdx.x;
  int e = tid * 4;
  int kt = e >> 6, sl = (e >> 3) & 7, off = e & 7;
  f4 acc = {0.f, 0.f, 0.f, 0.f};
  int s0 = cch * 128;
  const float* wrow = wt + b * SS;
  #pragma unroll 4
  for (int s = s0; s < s0 + 128; ++s) {
    float ws = wrow[s];
    int row = s * 64 + b;
    int panel = row >> 8, pr = row & 255, h = pr >> 7, r = pr & 127;
    size_t addr = (((size_t)panel * 16 + kt) * 2 + h) * 8192 + r * 64 + ((sl ^ (r & 7)) << 3) + off;
    ushort4 u = *(const ushort4*)(vbs + addr);
    acc[0] += bf2f(u.x) * ws;
    acc[1] += bf2f(u.y) * ws;
    acc[2] += bf2f(u.z) * ws;
    acc[3] += bf2f(u.w) * ws;
  }
  *(f4*)(ctxp + (size_t)(cch * 64 + b) * 1024 + tid * 4) = acc;
}

// ---- context fallback from f32 v (multi-chunk only)
__global__ void k_ctx_f32(const float* __restrict__ v, const float* __restrict__ wt,
                          float* __restrict__ ctxp) {
  int b = blockIdx.x, cch = blockIdx.y, tid = threadIdx.x;
  f4 acc = {0.f, 0.f, 0.f, 0.f};
  int s0 = cch * 128;
  const float* wrow = wt + b * SS;
  #pragma unroll 4
  for (int s = s0; s < s0 + 128; ++s) {
    float ws = wrow[s];
    const f4* vp = (const f4*)(v + (size_t)(s * 64 + b) * 1024);
    acc += vp[tid] * ws;
  }
  *(f4*)(ctxp + (size_t)(cch * 64 + b) * 1024 + tid * 4) = acc;
}

__global__ void k_out(const float* __restrict__ ctxp, float* __restrict__ out) {
  int b = blockIdx.x, tid = threadIdx.x;
  f4 acc = {0.f, 0.f, 0.f, 0.f};
  #pragma unroll
  for (int cch = 0; cch < 16; ++cch)
    acc += *(const f4*)(ctxp + (size_t)(cch * 64 + b) * 1024 + tid * 4);
  *(f4*)(out + b * 1024 + tid * 4) = acc;
}

extern "C" void kernel_launch(void* const* d_in, const int* in_sizes, int n_in,
                              void* d_out, int out_size, void* d_ws, size_t ws_size,
                              hipStream_t stream) {
  const float* hidden = (const float*)d_in[0];
  const float* v      = (const float*)d_in[1];   // (S, B, ENC) rows s*64+b
  const float* ww     = (const float*)d_in[2];   // (1024, 2048)
  const float* wbias  = (const float*)d_in[3];   // (1024)
  const float* vwgt   = (const float*)d_in[4];   // (1, 1024)
  float* out = (float*)d_out;

  char* ws = (char*)d_ws;
  float*          hp   = (float*)(ws);                                   // 256 KB
  unsigned short* wbs  = (unsigned short*)(ws + 262144);                 // 2 MB
  float*          part = (float*)(ws + 262144 + 2097152);                // 8 MB
  float*          wt   = (float*)(ws + 262144 + 2097152 + 8388608);      // 512 KB
  float*          ctxp = (float*)(ws + 262144 + 2097152 + 8388608 + 524288); // 4 MB
  size_t fixed = 262144 + 2097152 + 8388608 + 524288 + 4194304;
  unsigned short* vbs  = (unsigned short*)(ws + fixed);

  size_t avail = (ws_size > fixed) ? (ws_size - fixed) : 0;
  long rows_chunk = (long)(avail / 2048) & ~511L;      // multiple of 512 rows
  if (rows_chunk > MT) rows_chunk = MT;
  if (rows_chunk < 512) rows_chunk = 512;
  int nchunks = (int)((MT + rows_chunk - 1) / rows_chunk);

  hipFuncSetAttribute((const void*)k_gemm, hipFuncAttributeMaxDynamicSharedMemorySize, 131072);

  k_pack<<<dim3(16, 4), 256, 0, stream>>>(ww, wbs, 2048);
  k_hp<<<dim3(64, 4), 256, 0, stream>>>(hidden, ww, wbias, hp);

  for (long r0 = 0; r0 < MT; r0 += rows_chunk) {
    long nr = MT - r0; if (nr > rows_chunk) nr = rows_chunk;
    int nbm = (int)(nr / 256);
    k_pack<<<dim3((int)(nr / 64), 4), 256, 0, stream>>>(v + (size_t)r0 * 1024, vbs, 1024);
    k_gemm<<<nbm * 4, 512, 131072, stream>>>(vbs, wbs, hp, vwgt, part, (int)(r0 / 256), nbm);
  }

  k_softmax<<<64, 256, 0, stream>>>(part, wt);
  if (nchunks == 1)
    k_ctx_bfs<<<dim3(64, 16), 256, 0, stream>>>(vbs, wt, ctxp);
  else
    k_ctx_f32<<<dim3(64, 16), 256, 0, stream>>>(v, wt, ctxp);
  k_out<<<64, 256, 0, stream>>>(ctxp, out);
}